// Round 9
// baseline (178.254 us; speedup 1.0000x reference)
//
#include <hip/hip_runtime.h>
#include <hip/hip_fp16.h>
#include <hip/hip_fp8.h>
#include <math.h>

#define DIM 128

typedef _Float16 half8 __attribute__((ext_vector_type(8)));
typedef _Float16 half2v __attribute__((ext_vector_type(2)));
typedef float floatx4 __attribute__((ext_vector_type(4)));

// Storage column permutation: sigma(c) = (c&15)*8 + (c>>4), applied identically
// to H, R', T, W2 -> dot invariant. Verified in R5-R8 runs.

// ---------------------------------------------------------------------------
// MFMA precompute — unchanged from R8 (passed, ~15 us).
// ---------------------------------------------------------------------------
__global__ __launch_bounds__(256) void precompute(
    const float* __restrict__ h, const float* __restrict__ rel,
    const float* __restrict__ tim, const int* __restrict__ qrel,
    const float* __restrict__ W1, const float* __restrict__ b1,
    unsigned char* __restrict__ H8, __half* __restrict__ Rh, __half* __restrict__ Th,
    int n_nodes, int n_rels, int n_times, int nHB, int nRB)
{
    const int tid = threadIdx.x;
    const int b = blockIdx.x;

    const float* A; int M, k0, row0; bool isR = false, isH = false;
    __half* Out = nullptr;
    if (b < nHB)            { A = h;   isH = true; M = n_nodes; k0 = 0;   row0 = b * 128; }
    else if (b < nHB + nRB) { A = rel; Out = Rh;   M = n_rels;  k0 = 128; row0 = (b - nHB) * 128; isR = true; }
    else                    { A = tim; Out = Th;   M = n_times; k0 = 384; row0 = (b - nHB - nRB) * 128; }

    __shared__ _Float16 fragB[32 * 64 * 8];  // 32 KB: [ct*4+kc][lane][j]
    __shared__ float c0f[DIM];

#pragma unroll
    for (int it = 0; it < 8; ++it) {
        const int o = tid + it * 256;
        const int ctkc = o >> 6, L = o & 63;
        const int ct = ctkc >> 2, kc = ctkc & 3;
        const int q = L >> 4, n15 = L & 15;
        const float* base = W1 + (size_t)(k0 + kc * 32 + q * 8) * DIM + ct * 16 + n15;
        half8 f;
#pragma unroll
        for (int j = 0; j < 8; ++j) f[j] = (_Float16)base[(size_t)j * DIM];
        *(half8*)&fragB[o * 8] = f;
    }
    if (isR && tid < DIM) {  // c0[n] = b1[n] + rel[q] @ W1[256:384]
        const int q = qrel[0];
        const float* hq = rel + (size_t)q * DIM;
        float s = b1[tid];
        for (int k = 0; k < DIM; ++k)
            s = fmaf(hq[k], W1[(size_t)(256 + k) * DIM + tid], s);
        c0f[tid] = s;
    }
    __syncthreads();

    const int w = tid >> 6;
    const int lane = tid & 63;
    const int m15 = lane & 15, q = lane >> 4;

    const float* aBase[2];
#pragma unroll
    for (int mt = 0; mt < 2; ++mt) {
        int arow = row0 + w * 32 + mt * 16 + m15;
        if (arow >= M) arow = M - 1;
        aBase[mt] = A + (size_t)arow * DIM + q * 8;
    }

    floatx4 acc[2][8];
#pragma unroll
    for (int mt = 0; mt < 2; ++mt)
#pragma unroll
        for (int ct = 0; ct < 8; ++ct) acc[mt][ct] = (floatx4)0.f;

#pragma unroll
    for (int kc = 0; kc < 4; ++kc) {
        half8 af[2];
#pragma unroll
        for (int mt = 0; mt < 2; ++mt) {
            const float4 a0 = *(const float4*)(aBase[mt] + kc * 32);
            const float4 a1 = *(const float4*)(aBase[mt] + kc * 32 + 4);
            af[mt][0] = (_Float16)a0.x; af[mt][1] = (_Float16)a0.y;
            af[mt][2] = (_Float16)a0.z; af[mt][3] = (_Float16)a0.w;
            af[mt][4] = (_Float16)a1.x; af[mt][5] = (_Float16)a1.y;
            af[mt][6] = (_Float16)a1.z; af[mt][7] = (_Float16)a1.w;
        }
#pragma unroll
        for (int ct = 0; ct < 8; ++ct) {
            const half8 bf = *(half8*)&fragB[(((ct * 4 + kc) * 64) + lane) * 8];
            acc[0][ct] = __builtin_amdgcn_mfma_f32_16x16x32_f16(af[0], bf, acc[0][ct], 0, 0, 0);
            acc[1][ct] = __builtin_amdgcn_mfma_f32_16x16x32_f16(af[1], bf, acc[1][ct], 0, 0, 0);
        }
    }

    float cadd[8];
#pragma unroll
    for (int ct = 0; ct < 8; ++ct) cadd[ct] = isR ? c0f[ct * 16 + m15] : 0.f;

#pragma unroll
    for (int mt = 0; mt < 2; ++mt)
#pragma unroll
        for (int r = 0; r < 4; ++r) {
            const int m = row0 + w * 32 + mt * 16 + q * 4 + r;
            if (m < M) {
                if (isH) {
                    uint2 pk;
#if __has_builtin(__builtin_amdgcn_cvt_pk_fp8_f32)
                    int w0 = 0, w1 = 0;
                    w0 = __builtin_amdgcn_cvt_pk_fp8_f32(acc[mt][0][r], acc[mt][1][r], w0, false);
                    w0 = __builtin_amdgcn_cvt_pk_fp8_f32(acc[mt][2][r], acc[mt][3][r], w0, true);
                    w1 = __builtin_amdgcn_cvt_pk_fp8_f32(acc[mt][4][r], acc[mt][5][r], w1, false);
                    w1 = __builtin_amdgcn_cvt_pk_fp8_f32(acc[mt][6][r], acc[mt][7][r], w1, true);
                    pk.x = (unsigned)w0; pk.y = (unsigned)w1;
#else
                    union { uint2 u; unsigned char bb[8]; } pu;
#pragma unroll
                    for (int ct = 0; ct < 8; ++ct)
                        pu.bb[ct] = __hip_fp8_e4m3(acc[mt][ct][r]).__x;
                    pk = pu.u;
#endif
                    *(uint2*)(H8 + (size_t)m * DIM + m15 * 8) = pk;
                } else {
                    half8 hv;
#pragma unroll
                    for (int ct = 0; ct < 8; ++ct)
                        hv[ct] = (_Float16)(acc[mt][ct][r] + cadd[ct]);
                    *(half8*)(Out + (size_t)m * DIM + m15 * 8) = hv;
                }
            }
        }
}

// ---------------------------------------------------------------------------
// Edge kernel: cross-iteration software pipeline (2-phase, double-buffered
// gather registers + 2-deep index pipeline). Per 16-lane group, 4 edges/iter;
// gathers for iter i+1 are in flight while computing iter i (compiler emits
// vmcnt(N>0) instead of a full drain).
// out[e] = sigmoid(dot(relu(H[src]+R'[type]+T[time]), W2) + b2)
// ---------------------------------------------------------------------------
__device__ __forceinline__ half2v fp8x2_to_h2(unsigned u16) {
#if __has_builtin(__builtin_amdgcn_cvt_pk_f16_fp8)
    auto c = __builtin_amdgcn_cvt_pk_f16_fp8((short)u16);
    half2v r; r[0] = c[0]; r[1] = c[1];
    return r;
#else
    auto f = __builtin_amdgcn_cvt_pk_f32_fp8((int)u16, false);
    half2v r; r[0] = (_Float16)f[0]; r[1] = (_Float16)f[1];
    return r;
#endif
}

__device__ __forceinline__ float edot(uint2 hu, uint4 ru, uint4 tu,
                                      const half2v* __restrict__ w2h) {
    union U { uint4 u; half2v h[4]; };
    U R, T; R.u = ru; T.u = tu;
    const half2v z = (half2v)(_Float16)0.f;
    const unsigned hw[4] = {hu.x & 0xffffu, hu.x >> 16, hu.y & 0xffffu, hu.y >> 16};
    float p = 0.f;
#pragma unroll
    for (int j = 0; j < 4; ++j) {
        const half2v hh = fp8x2_to_h2(hw[j]);
        half2v s = hh + R.h[j] + T.h[j];
        s = __builtin_elementwise_max(s, z);
#if __has_builtin(__builtin_amdgcn_fdot2)
        p = __builtin_amdgcn_fdot2(s, w2h[j], p, false);
#else
        p = fmaf((float)s[0], (float)w2h[j][0], p);
        p = fmaf((float)s[1], (float)w2h[j][1], p);
#endif
    }
    return p;
}

struct GBuf { uint2 hv[4]; uint4 rv[4]; uint4 tv[4]; };

__device__ __forceinline__ void loadIdx(const int* __restrict__ ei,
                                        const int* __restrict__ ety,
                                        const int* __restrict__ eti,
                                        int qd, int E, bool exact,
                                        int* s, int* r, int* t) {
    const int e0 = 4 * qd;
    if (exact || e0 + 3 < E) {
#pragma unroll
        for (int i = 0; i < 4; ++i) { s[i] = ei[e0 + i]; r[i] = ety[e0 + i]; t[i] = eti[e0 + i]; }
    } else {
#pragma unroll
        for (int i = 0; i < 4; ++i) {
            const int e = min(e0 + i, E - 1);
            s[i] = ei[e]; r[i] = ety[e]; t[i] = eti[e];
        }
    }
}

__device__ __forceinline__ void gatherQuad(const unsigned char* __restrict__ H8,
                                           const __half* __restrict__ Rh,
                                           const __half* __restrict__ Th,
                                           const int* s, const int* r, const int* t,
                                           int l, GBuf& b) {
#pragma unroll
    for (int i = 0; i < 4; ++i) {
        b.hv[i] = ((const uint2*)(H8 + (size_t)s[i] * DIM))[l];
        b.rv[i] = ((const uint4*)(Rh + (size_t)r[i] * DIM))[l];
        b.tv[i] = ((const uint4*)(Th + (size_t)t[i] * DIM))[l];
    }
}

__device__ __forceinline__ void computeStore(const GBuf& bu, int g, int E, int l,
                                             const half2v* w2h, float b2v,
                                             float* __restrict__ out) {
    float p[4];
#pragma unroll
    for (int i = 0; i < 4; ++i)
        p[i] = edot(bu.hv[i], bu.rv[i], bu.tv[i], w2h);
#pragma unroll
    for (int off = 8; off > 0; off >>= 1) {
#pragma unroll
        for (int i = 0; i < 4; ++i)
            p[i] += __shfl_down(p[i], off, 16);
    }
    if (l == 0) {
        const int e0 = 4 * g;
        float4 o;
        o.x = 1.f / (1.f + __expf(-(p[0] + b2v)));
        o.y = 1.f / (1.f + __expf(-(p[1] + b2v)));
        o.z = 1.f / (1.f + __expf(-(p[2] + b2v)));
        o.w = 1.f / (1.f + __expf(-(p[3] + b2v)));
        if (e0 + 3 < E) {
            *(float4*)(out + e0) = o;
        } else {
            const float ov[4] = {o.x, o.y, o.z, o.w};
            for (int i = 0; i < 4 && e0 + i < E; ++i) out[e0 + i] = ov[i];
        }
    }
}

__global__ __launch_bounds__(256) void edge_kernel(
    const int* __restrict__ ei, const int* __restrict__ ety,
    const int* __restrict__ eti,
    const unsigned char* __restrict__ H8, const __half* __restrict__ Rh,
    const __half* __restrict__ Th,
    const float* __restrict__ W2, const float* __restrict__ b2,
    float* __restrict__ out, int E, int nGrpTotal)
{
    const int tid = threadIdx.x;
    const int l = tid & 15;
    int g = blockIdx.x * 16 + (tid >> 4);
    const int nQuad = (E + 3) >> 2;
    if (g >= nQuad) return;

    half2v w2h[4];
#pragma unroll
    for (int j = 0; j < 4; ++j) {
        w2h[j][0] = (_Float16)W2[(2 * j) * 16 + l];
        w2h[j][1] = (_Float16)W2[(2 * j + 1) * 16 + l];
    }
    const float b2v = b2[0];
    const bool exact = (E & 3) == 0;
    const int stride = nGrpTotal;

    int sA[4], rA[4], tA[4], sB[4], rB[4], tB[4];
    GBuf bufA, bufB;

    // Prologue: idx(g) -> gather bufA; idx for gn (clamped).
    loadIdx(ei, ety, eti, g, E, exact, sA, rA, tA);
    gatherQuad(H8, Rh, Th, sA, rA, tA, l, bufA);
    int gn = g + stride;
    loadIdx(ei, ety, eti, min(gn, nQuad - 1), E, exact, sB, rB, tB);

    while (true) {
        // Phase 1: gathers for gn in flight while computing g.
        gatherQuad(H8, Rh, Th, sB, rB, tB, l, bufB);
        int g2 = gn + stride;
        loadIdx(ei, ety, eti, min(g2, nQuad - 1), E, exact, sA, rA, tA);
        computeStore(bufA, g, E, l, w2h, b2v, out);
        if (gn >= nQuad) break;

        // Phase 2: mirror (buffers swapped).
        gatherQuad(H8, Rh, Th, sA, rA, tA, l, bufA);
        int g3 = g2 + stride;
        loadIdx(ei, ety, eti, min(g3, nQuad - 1), E, exact, sB, rB, tB);
        computeStore(bufB, gn, E, l, w2h, b2v, out);
        if (g2 >= nQuad) break;

        g = g2; gn = g3;
    }
}

extern "C" void kernel_launch(void* const* d_in, const int* in_sizes, int n_in,
                              void* d_out, int out_size, void* d_ws, size_t ws_size,
                              hipStream_t stream) {
    const float* h          = (const float*)d_in[0];
    const int*   edge_index = (const int*)d_in[1];   // [2,E] flat; row 0 = src
    const int*   edge_type  = (const int*)d_in[2];
    const int*   edge_time  = (const int*)d_in[3];
    const int*   query_rel  = (const int*)d_in[4];
    const float* rel_table  = (const float*)d_in[5];
    const float* time_table = (const float*)d_in[6];
    const float* W1         = (const float*)d_in[7]; // [512,128] row-major
    const float* b1         = (const float*)d_in[8];
    const float* W2         = (const float*)d_in[9]; // [128,1]
    const float* b2         = (const float*)d_in[10];
    float* out = (float*)d_out;

    const int n_nodes = in_sizes[0] / DIM;
    const int E       = in_sizes[2];
    const int n_rels  = in_sizes[5] / DIM;
    const int n_times = in_sizes[6] / DIM;

    unsigned char* H8 = (unsigned char*)d_ws;                    // n_nodes*128 B
    __half* Rh = (__half*)(H8 + (((size_t)n_nodes * DIM + 255) & ~(size_t)255));
    __half* Th = Rh + (size_t)n_rels * DIM;

    const int nHB = (n_nodes + 127) / 128;
    const int nRB = (n_rels + 127) / 128;
    const int nTB = (n_times + 127) / 128;

    precompute<<<nHB + nRB + nTB, 256, 0, stream>>>(
        h, rel_table, time_table, query_rel, W1, b1,
        H8, Rh, Th, n_nodes, n_rels, n_times, nHB, nRB);

    const int nBlk = 4096;  // 2x oversubscription, grid-stride
    edge_kernel<<<nBlk, 256, 0, stream>>>(
        edge_index, edge_type, edge_time, H8, Rh, Th, W2, b2,
        out, E, nBlk * 16);
}

// Round 10
// 163.526 us; speedup vs baseline: 1.0901x; 1.0901x over previous
//
#include <hip/hip_runtime.h>
#include <hip/hip_fp16.h>
#include <hip/hip_fp8.h>
#include <math.h>

#define DIM 128

typedef _Float16 half8 __attribute__((ext_vector_type(8)));
typedef _Float16 half2v __attribute__((ext_vector_type(2)));
typedef float floatx4 __attribute__((ext_vector_type(4)));

// Storage column permutation: sigma(c) = (c&15)*8 + (c>>4), applied identically
// to H, R', T, W2 -> dot invariant. Verified in R5-R9 runs.

// ---------------------------------------------------------------------------
// MFMA precompute (R8 base + hoisted A-loads):
//   blocks [0,nHB)        : H  = h          @ W1[  0:128]            -> fp8 e4m3
//   blocks [nHB,+nRB)     : R' = rel_table  @ W1[128:256] + c0       -> fp16
//   blocks [nHB+nRB,...)  : T  = time_table @ W1[384:512]            -> fp16
// All 16 A float4 loads issued before the MFMA loop (single latency wait
// instead of one per kc iteration).
// ---------------------------------------------------------------------------
__global__ __launch_bounds__(256) void precompute(
    const float* __restrict__ h, const float* __restrict__ rel,
    const float* __restrict__ tim, const int* __restrict__ qrel,
    const float* __restrict__ W1, const float* __restrict__ b1,
    unsigned char* __restrict__ H8, __half* __restrict__ Rh, __half* __restrict__ Th,
    int n_nodes, int n_rels, int n_times, int nHB, int nRB)
{
    const int tid = threadIdx.x;
    const int b = blockIdx.x;

    const float* A; int M, k0, row0; bool isR = false, isH = false;
    __half* Out = nullptr;
    if (b < nHB)            { A = h;   isH = true; M = n_nodes; k0 = 0;   row0 = b * 128; }
    else if (b < nHB + nRB) { A = rel; Out = Rh;   M = n_rels;  k0 = 128; row0 = (b - nHB) * 128; isR = true; }
    else                    { A = tim; Out = Th;   M = n_times; k0 = 384; row0 = (b - nHB - nRB) * 128; }

    __shared__ _Float16 fragB[32 * 64 * 8];  // 32 KB: [ct*4+kc][lane][j]
    __shared__ float c0f[DIM];

    const int w = tid >> 6;
    const int lane = tid & 63;
    const int m15 = lane & 15, q = lane >> 4;

    // Hoist ALL A-loads (independent of LDS staging) — issue before staging
    // so global latency overlaps the staging work.
    const float* aBase[2];
#pragma unroll
    for (int mt = 0; mt < 2; ++mt) {
        int arow = row0 + w * 32 + mt * 16 + m15;
        if (arow >= M) arow = M - 1;
        aBase[mt] = A + (size_t)arow * DIM + q * 8;
    }
    float4 aReg[2][8];
#pragma unroll
    for (int mt = 0; mt < 2; ++mt)
#pragma unroll
        for (int kc = 0; kc < 4; ++kc) {
            aReg[mt][2 * kc]     = *(const float4*)(aBase[mt] + kc * 32);
            aReg[mt][2 * kc + 1] = *(const float4*)(aBase[mt] + kc * 32 + 4);
        }

    // Conflict-free B-fragment staging: thread -> one octet per iter.
#pragma unroll
    for (int it = 0; it < 8; ++it) {
        const int o = tid + it * 256;
        const int ctkc = o >> 6, L = o & 63;
        const int ct = ctkc >> 2, kc = ctkc & 3;
        const int qq = L >> 4, n15 = L & 15;
        const float* base = W1 + (size_t)(k0 + kc * 32 + qq * 8) * DIM + ct * 16 + n15;
        half8 f;
#pragma unroll
        for (int j = 0; j < 8; ++j) f[j] = (_Float16)base[(size_t)j * DIM];
        *(half8*)&fragB[o * 8] = f;
    }
    if (isR && tid < DIM) {  // c0[n] = b1[n] + rel[q] @ W1[256:384]
        const int qi = qrel[0];
        const float* hq = rel + (size_t)qi * DIM;
        float s = b1[tid];
        for (int k = 0; k < DIM; ++k)
            s = fmaf(hq[k], W1[(size_t)(256 + k) * DIM + tid], s);
        c0f[tid] = s;
    }
    __syncthreads();

    floatx4 acc[2][8];
#pragma unroll
    for (int mt = 0; mt < 2; ++mt)
#pragma unroll
        for (int ct = 0; ct < 8; ++ct) acc[mt][ct] = (floatx4)0.f;

#pragma unroll
    for (int kc = 0; kc < 4; ++kc) {
        half8 af[2];
#pragma unroll
        for (int mt = 0; mt < 2; ++mt) {
            const float4 a0 = aReg[mt][2 * kc];
            const float4 a1 = aReg[mt][2 * kc + 1];
            af[mt][0] = (_Float16)a0.x; af[mt][1] = (_Float16)a0.y;
            af[mt][2] = (_Float16)a0.z; af[mt][3] = (_Float16)a0.w;
            af[mt][4] = (_Float16)a1.x; af[mt][5] = (_Float16)a1.y;
            af[mt][6] = (_Float16)a1.z; af[mt][7] = (_Float16)a1.w;
        }
#pragma unroll
        for (int ct = 0; ct < 8; ++ct) {
            const half8 bf = *(half8*)&fragB[(((ct * 4 + kc) * 64) + lane) * 8];
            acc[0][ct] = __builtin_amdgcn_mfma_f32_16x16x32_f16(af[0], bf, acc[0][ct], 0, 0, 0);
            acc[1][ct] = __builtin_amdgcn_mfma_f32_16x16x32_f16(af[1], bf, acc[1][ct], 0, 0, 0);
        }
    }

    float cadd[8];
#pragma unroll
    for (int ct = 0; ct < 8; ++ct) cadd[ct] = isR ? c0f[ct * 16 + m15] : 0.f;

    // Permuted epilogue. C/D layout: col = lane&15, row = (lane>>4)*4 + reg.
#pragma unroll
    for (int mt = 0; mt < 2; ++mt)
#pragma unroll
        for (int r = 0; r < 4; ++r) {
            const int m = row0 + w * 32 + mt * 16 + q * 4 + r;
            if (m < M) {
                if (isH) {
                    uint2 pk;
#if __has_builtin(__builtin_amdgcn_cvt_pk_fp8_f32)
                    int w0 = 0, w1 = 0;
                    w0 = __builtin_amdgcn_cvt_pk_fp8_f32(acc[mt][0][r], acc[mt][1][r], w0, false);
                    w0 = __builtin_amdgcn_cvt_pk_fp8_f32(acc[mt][2][r], acc[mt][3][r], w0, true);
                    w1 = __builtin_amdgcn_cvt_pk_fp8_f32(acc[mt][4][r], acc[mt][5][r], w1, false);
                    w1 = __builtin_amdgcn_cvt_pk_fp8_f32(acc[mt][6][r], acc[mt][7][r], w1, true);
                    pk.x = (unsigned)w0; pk.y = (unsigned)w1;
#else
                    union { uint2 u; unsigned char bb[8]; } pu;
#pragma unroll
                    for (int ct = 0; ct < 8; ++ct)
                        pu.bb[ct] = __hip_fp8_e4m3(acc[mt][ct][r]).__x;
                    pk = pu.u;
#endif
                    *(uint2*)(H8 + (size_t)m * DIM + m15 * 8) = pk;
                } else {
                    half8 hv;
#pragma unroll
                    for (int ct = 0; ct < 8; ++ct)
                        hv[ct] = (_Float16)(acc[mt][ct][r] + cadd[ct]);
                    *(half8*)(Out + (size_t)m * DIM + m15 * 8) = hv;
                }
            }
        }
}

// ---------------------------------------------------------------------------
// Edge kernel — exact R8 structure (best measured: ~43 us, VGPR 40) with one
// change: quad indices loaded as int4 vector loads (3 VMEM instead of 12).
// out[e] = sigmoid(dot(relu(H[src]+R'[type]+T[time]), W2) + b2)
// ---------------------------------------------------------------------------
__device__ __forceinline__ half2v fp8x2_to_h2(unsigned u16) {
#if __has_builtin(__builtin_amdgcn_cvt_pk_f16_fp8)
    auto c = __builtin_amdgcn_cvt_pk_f16_fp8((short)u16);
    half2v r; r[0] = c[0]; r[1] = c[1];
    return r;
#else
    auto f = __builtin_amdgcn_cvt_pk_f32_fp8((int)u16, false);
    half2v r; r[0] = (_Float16)f[0]; r[1] = (_Float16)f[1];
    return r;
#endif
}

__device__ __forceinline__ float edot(uint2 hu, uint4 ru, uint4 tu,
                                      const half2v* __restrict__ w2h) {
    union U { uint4 u; half2v h[4]; };
    U R, T; R.u = ru; T.u = tu;
    const half2v z = (half2v)(_Float16)0.f;
    const unsigned hw[4] = {hu.x & 0xffffu, hu.x >> 16, hu.y & 0xffffu, hu.y >> 16};
    float p = 0.f;
#pragma unroll
    for (int j = 0; j < 4; ++j) {
        const half2v hh = fp8x2_to_h2(hw[j]);
        half2v s = hh + R.h[j] + T.h[j];
        s = __builtin_elementwise_max(s, z);
#if __has_builtin(__builtin_amdgcn_fdot2)
        p = __builtin_amdgcn_fdot2(s, w2h[j], p, false);
#else
        p = fmaf((float)s[0], (float)w2h[j][0], p);
        p = fmaf((float)s[1], (float)w2h[j][1], p);
#endif
    }
    return p;
}

__global__ __launch_bounds__(256) void edge_kernel(
    const int* __restrict__ ei, const int* __restrict__ ety,
    const int* __restrict__ eti,
    const unsigned char* __restrict__ H8, const __half* __restrict__ Rh,
    const __half* __restrict__ Th,
    const float* __restrict__ W2, const float* __restrict__ b2,
    float* __restrict__ out, int E, int nGrpTotal)
{
    const int tid = threadIdx.x;
    const int l = tid & 15;
    int g = blockIdx.x * 16 + (tid >> 4);
    const int nQuad = (E + 3) >> 2;
    if (g >= nQuad) return;

    half2v w2h[4];
#pragma unroll
    for (int j = 0; j < 4; ++j) {
        w2h[j][0] = (_Float16)W2[(2 * j) * 16 + l];
        w2h[j][1] = (_Float16)W2[(2 * j + 1) * 16 + l];
    }
    const float b2v = b2[0];

    int s[4], r[4], t[4];
    {
        const int e0 = 4 * g;
        if (e0 + 3 < E) {
            const int4 sv = *(const int4*)(ei + e0);
            const int4 rv4 = *(const int4*)(ety + e0);
            const int4 tv4 = *(const int4*)(eti + e0);
            s[0] = sv.x; s[1] = sv.y; s[2] = sv.z; s[3] = sv.w;
            r[0] = rv4.x; r[1] = rv4.y; r[2] = rv4.z; r[3] = rv4.w;
            t[0] = tv4.x; t[1] = tv4.y; t[2] = tv4.z; t[3] = tv4.w;
        } else {
#pragma unroll
            for (int i = 0; i < 4; ++i) {
                const int e = min(e0 + i, E - 1);
                s[i] = ei[e]; r[i] = ety[e]; t[i] = eti[e];
            }
        }
    }

    while (true) {
        const int gn = g + nGrpTotal;
        // 12 gathers in flight
        uint2 hv[4]; uint4 rv[4], tv[4];
#pragma unroll
        for (int i = 0; i < 4; ++i) {
            hv[i] = ((const uint2*)(H8 + (size_t)s[i] * DIM))[l];
            rv[i] = ((const uint4*)(Rh + (size_t)r[i] * DIM))[l];
            tv[i] = ((const uint4*)(Th + (size_t)t[i] * DIM))[l];
        }
        if (gn < nQuad) {  // prefetch next indices while gathers land
            const int e0 = 4 * gn;
            if (e0 + 3 < E) {
                const int4 sv = *(const int4*)(ei + e0);
                const int4 rv4 = *(const int4*)(ety + e0);
                const int4 tv4 = *(const int4*)(eti + e0);
                s[0] = sv.x; s[1] = sv.y; s[2] = sv.z; s[3] = sv.w;
                r[0] = rv4.x; r[1] = rv4.y; r[2] = rv4.z; r[3] = rv4.w;
                t[0] = tv4.x; t[1] = tv4.y; t[2] = tv4.z; t[3] = tv4.w;
            } else {
#pragma unroll
                for (int i = 0; i < 4; ++i) {
                    const int e = min(e0 + i, E - 1);
                    s[i] = ei[e]; r[i] = ety[e]; t[i] = eti[e];
                }
            }
        }
        float p[4];
#pragma unroll
        for (int i = 0; i < 4; ++i)
            p[i] = edot(hv[i], rv[i], tv[i], w2h);
#pragma unroll
        for (int off = 8; off > 0; off >>= 1) {
#pragma unroll
            for (int i = 0; i < 4; ++i)
                p[i] += __shfl_down(p[i], off, 16);
        }
        if (l == 0) {
            const int e0 = 4 * g;
            float4 o;
            o.x = 1.f / (1.f + __expf(-(p[0] + b2v)));
            o.y = 1.f / (1.f + __expf(-(p[1] + b2v)));
            o.z = 1.f / (1.f + __expf(-(p[2] + b2v)));
            o.w = 1.f / (1.f + __expf(-(p[3] + b2v)));
            if (e0 + 3 < E) {
                *(float4*)(out + e0) = o;
            } else {
                const float ov[4] = {o.x, o.y, o.z, o.w};
                for (int i = 0; i < 4 && e0 + i < E; ++i) out[e0 + i] = ov[i];
            }
        }
        if (gn >= nQuad) break;
        g = gn;
    }
}

extern "C" void kernel_launch(void* const* d_in, const int* in_sizes, int n_in,
                              void* d_out, int out_size, void* d_ws, size_t ws_size,
                              hipStream_t stream) {
    const float* h          = (const float*)d_in[0];
    const int*   edge_index = (const int*)d_in[1];   // [2,E] flat; row 0 = src
    const int*   edge_type  = (const int*)d_in[2];
    const int*   edge_time  = (const int*)d_in[3];
    const int*   query_rel  = (const int*)d_in[4];
    const float* rel_table  = (const float*)d_in[5];
    const float* time_table = (const float*)d_in[6];
    const float* W1         = (const float*)d_in[7]; // [512,128] row-major
    const float* b1         = (const float*)d_in[8];
    const float* W2         = (const float*)d_in[9]; // [128,1]
    const float* b2         = (const float*)d_in[10];
    float* out = (float*)d_out;

    const int n_nodes = in_sizes[0] / DIM;
    const int E       = in_sizes[2];
    const int n_rels  = in_sizes[5] / DIM;
    const int n_times = in_sizes[6] / DIM;

    unsigned char* H8 = (unsigned char*)d_ws;                    // n_nodes*128 B
    __half* Rh = (__half*)(H8 + (((size_t)n_nodes * DIM + 255) & ~(size_t)255));
    __half* Th = Rh + (size_t)n_rels * DIM;

    const int nHB = (n_nodes + 127) / 128;
    const int nRB = (n_rels + 127) / 128;
    const int nTB = (n_times + 127) / 128;

    precompute<<<nHB + nRB + nTB, 256, 0, stream>>>(
        h, rel_table, time_table, query_rel, W1, b1,
        H8, Rh, Th, n_nodes, n_rels, n_times, nHB, nRB);

    const int nBlk = 4096;  // 2x oversubscription, grid-stride
    edge_kernel<<<nBlk, 256, 0, stream>>>(
        edge_index, edge_type, edge_time, H8, Rh, Th, W2, b2,
        out, E, nBlk * 16);
}

// Round 11
// 159.216 us; speedup vs baseline: 1.1196x; 1.0271x over previous
//
#include <hip/hip_runtime.h>
#include <hip/hip_fp16.h>
#include <hip/hip_fp8.h>
#include <math.h>

#define DIM 128

typedef _Float16 half8 __attribute__((ext_vector_type(8)));
typedef _Float16 half2v __attribute__((ext_vector_type(2)));
typedef float floatx4 __attribute__((ext_vector_type(4)));

// Storage column permutation: sigma(c) = (c&15)*8 + (c>>4); inverse
// c = 16*(p&7) + (p>>3). Applied identically to H, R', T, W2 -> dot
// invariant. Verified in R5-R10 runs.

// ---------------------------------------------------------------------------
// MFMA precompute — R8 verbatim (known-good, ~15 us):
//   blocks [0,nHB)        : H  = h          @ W1[  0:128]            -> fp8 e4m3
//   blocks [nHB,+nRB)     : R' = rel_table  @ W1[128:256] + c0       -> fp16
//   blocks [nHB+nRB,...)  : T  = time_table @ W1[384:512]            -> fp16
// ---------------------------------------------------------------------------
__global__ __launch_bounds__(256) void precompute(
    const float* __restrict__ h, const float* __restrict__ rel,
    const float* __restrict__ tim, const int* __restrict__ qrel,
    const float* __restrict__ W1, const float* __restrict__ b1,
    unsigned char* __restrict__ H8, __half* __restrict__ Rh, __half* __restrict__ Th,
    int n_nodes, int n_rels, int n_times, int nHB, int nRB)
{
    const int tid = threadIdx.x;
    const int b = blockIdx.x;

    const float* A; int M, k0, row0; bool isR = false, isH = false;
    __half* Out = nullptr;
    if (b < nHB)            { A = h;   isH = true; M = n_nodes; k0 = 0;   row0 = b * 128; }
    else if (b < nHB + nRB) { A = rel; Out = Rh;   M = n_rels;  k0 = 128; row0 = (b - nHB) * 128; isR = true; }
    else                    { A = tim; Out = Th;   M = n_times; k0 = 384; row0 = (b - nHB - nRB) * 128; }

    __shared__ _Float16 fragB[32 * 64 * 8];  // 32 KB: [ct*4+kc][lane][j]
    __shared__ float c0f[DIM];

#pragma unroll
    for (int it = 0; it < 8; ++it) {
        const int o = tid + it * 256;
        const int ctkc = o >> 6, L = o & 63;
        const int ct = ctkc >> 2, kc = ctkc & 3;
        const int q = L >> 4, n15 = L & 15;
        const float* base = W1 + (size_t)(k0 + kc * 32 + q * 8) * DIM + ct * 16 + n15;
        half8 f;
#pragma unroll
        for (int j = 0; j < 8; ++j) f[j] = (_Float16)base[(size_t)j * DIM];
        *(half8*)&fragB[o * 8] = f;
    }
    if (isR && tid < DIM) {  // c0[n] = b1[n] + rel[q] @ W1[256:384]
        const int q = qrel[0];
        const float* hq = rel + (size_t)q * DIM;
        float s = b1[tid];
        for (int k = 0; k < DIM; ++k)
            s = fmaf(hq[k], W1[(size_t)(256 + k) * DIM + tid], s);
        c0f[tid] = s;
    }
    __syncthreads();

    const int w = tid >> 6;
    const int lane = tid & 63;
    const int m15 = lane & 15, q = lane >> 4;

    const float* aBase[2];
#pragma unroll
    for (int mt = 0; mt < 2; ++mt) {
        int arow = row0 + w * 32 + mt * 16 + m15;
        if (arow >= M) arow = M - 1;
        aBase[mt] = A + (size_t)arow * DIM + q * 8;
    }

    floatx4 acc[2][8];
#pragma unroll
    for (int mt = 0; mt < 2; ++mt)
#pragma unroll
        for (int ct = 0; ct < 8; ++ct) acc[mt][ct] = (floatx4)0.f;

#pragma unroll
    for (int kc = 0; kc < 4; ++kc) {
        half8 af[2];
#pragma unroll
        for (int mt = 0; mt < 2; ++mt) {
            const float4 a0 = *(const float4*)(aBase[mt] + kc * 32);
            const float4 a1 = *(const float4*)(aBase[mt] + kc * 32 + 4);
            af[mt][0] = (_Float16)a0.x; af[mt][1] = (_Float16)a0.y;
            af[mt][2] = (_Float16)a0.z; af[mt][3] = (_Float16)a0.w;
            af[mt][4] = (_Float16)a1.x; af[mt][5] = (_Float16)a1.y;
            af[mt][6] = (_Float16)a1.z; af[mt][7] = (_Float16)a1.w;
        }
#pragma unroll
        for (int ct = 0; ct < 8; ++ct) {
            const half8 bf = *(half8*)&fragB[(((ct * 4 + kc) * 64) + lane) * 8];
            acc[0][ct] = __builtin_amdgcn_mfma_f32_16x16x32_f16(af[0], bf, acc[0][ct], 0, 0, 0);
            acc[1][ct] = __builtin_amdgcn_mfma_f32_16x16x32_f16(af[1], bf, acc[1][ct], 0, 0, 0);
        }
    }

    float cadd[8];
#pragma unroll
    for (int ct = 0; ct < 8; ++ct) cadd[ct] = isR ? c0f[ct * 16 + m15] : 0.f;

#pragma unroll
    for (int mt = 0; mt < 2; ++mt)
#pragma unroll
        for (int r = 0; r < 4; ++r) {
            const int m = row0 + w * 32 + mt * 16 + q * 4 + r;
            if (m < M) {
                if (isH) {
                    uint2 pk;
#if __has_builtin(__builtin_amdgcn_cvt_pk_fp8_f32)
                    int w0 = 0, w1 = 0;
                    w0 = __builtin_amdgcn_cvt_pk_fp8_f32(acc[mt][0][r], acc[mt][1][r], w0, false);
                    w0 = __builtin_amdgcn_cvt_pk_fp8_f32(acc[mt][2][r], acc[mt][3][r], w0, true);
                    w1 = __builtin_amdgcn_cvt_pk_fp8_f32(acc[mt][4][r], acc[mt][5][r], w1, false);
                    w1 = __builtin_amdgcn_cvt_pk_fp8_f32(acc[mt][6][r], acc[mt][7][r], w1, true);
                    pk.x = (unsigned)w0; pk.y = (unsigned)w1;
#else
                    union { uint2 u; unsigned char bb[8]; } pu;
#pragma unroll
                    for (int ct = 0; ct < 8; ++ct)
                        pu.bb[ct] = __hip_fp8_e4m3(acc[mt][ct][r]).__x;
                    pk = pu.u;
#endif
                    *(uint2*)(H8 + (size_t)m * DIM + m15 * 8) = pk;
                } else {
                    half8 hv;
#pragma unroll
                    for (int ct = 0; ct < 8; ++ct)
                        hv[ct] = (_Float16)(acc[mt][ct][r] + cadd[ct]);
                    *(half8*)(Out + (size_t)m * DIM + m15 * 8) = hv;
                }
            }
        }
}

// ---------------------------------------------------------------------------
// Edge kernel: 8 lanes per edge (uint4 fp8 H = full row; 2x uint4 fp16 R/T).
// One wave = 8 edges/iter -> 5 gather + ~40 VALU wave-instrs per 8 edges
// (4-5x fewer issue slots per edge than the 16-lane R8 version).
// Persistent grid-stride + index prefetch; no gather double-buffering
// (TLP over ILP -- R9 lesson).
// out[e] = sigmoid(dot(relu(H[src]+R'[type]+T[time]), W2) + b2)
// ---------------------------------------------------------------------------
__device__ __forceinline__ half2v fp8x2_to_h2(unsigned u16) {
#if __has_builtin(__builtin_amdgcn_cvt_pk_f16_fp8)
    auto c = __builtin_amdgcn_cvt_pk_f16_fp8((short)u16);
    half2v r; r[0] = c[0]; r[1] = c[1];
    return r;
#else
    auto f = __builtin_amdgcn_cvt_pk_f32_fp8((int)u16, false);
    half2v r; r[0] = (_Float16)f[0]; r[1] = (_Float16)f[1];
    return r;
#endif
}

__device__ __forceinline__ float edot16(uint4 hu, uint4 r0, uint4 r1,
                                        uint4 t0, uint4 t1,
                                        const half2v* __restrict__ w2h) {
    union U { uint4 u; half2v h[4]; };
    U R0, R1, T0, T1; R0.u = r0; R1.u = r1; T0.u = t0; T1.u = t1;
    const half2v z = (half2v)(_Float16)0.f;
    const unsigned hw[8] = {hu.x & 0xffffu, hu.x >> 16, hu.y & 0xffffu, hu.y >> 16,
                            hu.z & 0xffffu, hu.z >> 16, hu.w & 0xffffu, hu.w >> 16};
    float p = 0.f;
#pragma unroll
    for (int j = 0; j < 8; ++j) {
        const half2v rr = (j < 4) ? R0.h[j] : R1.h[j - 4];
        const half2v tt = (j < 4) ? T0.h[j] : T1.h[j - 4];
        half2v s = fp8x2_to_h2(hw[j]) + rr + tt;          // v_pk_add_f16 x2
        s = __builtin_elementwise_max(s, z);              // v_pk_max_f16
#if __has_builtin(__builtin_amdgcn_fdot2)
        p = __builtin_amdgcn_fdot2(s, w2h[j], p, false);  // v_dot2_f32_f16
#else
        p = fmaf((float)s[0], (float)w2h[j][0], p);
        p = fmaf((float)s[1], (float)w2h[j][1], p);
#endif
    }
    return p;
}

__global__ __launch_bounds__(256) void edge_kernel(
    const int* __restrict__ ei, const int* __restrict__ ety,
    const int* __restrict__ eti,
    const unsigned char* __restrict__ H8, const __half* __restrict__ Rh,
    const __half* __restrict__ Th,
    const float* __restrict__ W2, const float* __restrict__ b2,
    float* __restrict__ out, int E, int nGrpTotal)
{
    const int tid = threadIdx.x;
    const int l = tid & 7;                    // lane within 8-lane group
    int e = blockIdx.x * 32 + (tid >> 3);     // 32 groups per 256-thr block
    if (e >= E) return;

    // W2 lane map (from inverse permutation c = 16*(p&7) + (p>>3)):
    // lane l, byte-pair j: j<4 -> cols (32j+2l, 32j+16+2l); j>=4 -> +1.
    half2v w2h[8];
#pragma unroll
    for (int j = 0; j < 4; ++j) {
        w2h[j][0]     = (_Float16)W2[32 * j + 2 * l];
        w2h[j][1]     = (_Float16)W2[32 * j + 16 + 2 * l];
        w2h[j + 4][0] = (_Float16)W2[32 * j + 2 * l + 1];
        w2h[j + 4][1] = (_Float16)W2[32 * j + 16 + 2 * l + 1];
    }
    const float b2v = b2[0];
    const int stride = nGrpTotal;

    int s = ei[e], r = ety[e], t = eti[e];

    while (true) {
        const int en = e + stride;
        // 5 gathers in flight (each 64 lanes x 16 B = 1 KB, fully utilized)
        const uint4* hp = (const uint4*)(H8 + (size_t)s * DIM);
        const uint4* rp = (const uint4*)(Rh + (size_t)r * DIM);
        const uint4* tp = (const uint4*)(Th + (size_t)t * DIM);
        const uint4 hv  = hp[l];
        const uint4 rv0 = rp[2 * l], rv1 = rp[2 * l + 1];
        const uint4 tv0 = tp[2 * l], tv1 = tp[2 * l + 1];
        if (en < E) {  // prefetch next indices while gathers land
            s = ei[en]; r = ety[en]; t = eti[en];
        }
        float p = edot16(hv, rv0, rv1, tv0, tv1, w2h);
        p += __shfl_down(p, 4, 8);
        p += __shfl_down(p, 2, 8);
        p += __shfl_down(p, 1, 8);
        if (l == 0)
            out[e] = 1.f / (1.f + __expf(-(p + b2v)));
        if (en >= E) break;
        e = en;
    }
}

extern "C" void kernel_launch(void* const* d_in, const int* in_sizes, int n_in,
                              void* d_out, int out_size, void* d_ws, size_t ws_size,
                              hipStream_t stream) {
    const float* h          = (const float*)d_in[0];
    const int*   edge_index = (const int*)d_in[1];   // [2,E] flat; row 0 = src
    const int*   edge_type  = (const int*)d_in[2];
    const int*   edge_time  = (const int*)d_in[3];
    const int*   query_rel  = (const int*)d_in[4];
    const float* rel_table  = (const float*)d_in[5];
    const float* time_table = (const float*)d_in[6];
    const float* W1         = (const float*)d_in[7]; // [512,128] row-major
    const float* b1         = (const float*)d_in[8];
    const float* W2         = (const float*)d_in[9]; // [128,1]
    const float* b2         = (const float*)d_in[10];
    float* out = (float*)d_out;

    const int n_nodes = in_sizes[0] / DIM;
    const int E       = in_sizes[2];
    const int n_rels  = in_sizes[5] / DIM;
    const int n_times = in_sizes[6] / DIM;

    unsigned char* H8 = (unsigned char*)d_ws;                    // n_nodes*128 B
    __half* Rh = (__half*)(H8 + (((size_t)n_nodes * DIM + 255) & ~(size_t)255));
    __half* Th = Rh + (size_t)n_rels * DIM;

    const int nHB = (n_nodes + 127) / 128;
    const int nRB = (n_rels + 127) / 128;
    const int nTB = (n_times + 127) / 128;

    precompute<<<nHB + nRB + nTB, 256, 0, stream>>>(
        h, rel_table, time_table, query_rel, W1, b1,
        H8, Rh, Th, n_nodes, n_rels, n_times, nHB, nRB);

    const int nBlk = 4096;  // 32 groups/block -> 131072 groups, grid-stride
    edge_kernel<<<nBlk, 256, 0, stream>>>(
        edge_index, edge_type, edge_time, H8, Rh, Th, W2, b2,
        out, E, nBlk * 32);
}